// Round 2
// 930.115 us; speedup vs baseline: 1.0089x; 1.0089x over previous
//
#include <hip/hip_runtime.h>
#include <hip/hip_bf16.h>

// SpatialGather split into 3 kernels:
//  1) sg_softmax: p[k,n] = softmax_k(logits[:,n]) as bf16 (row-major [160][N], rows 150+ garbage)
//                 + colsum[k] = sum_n p[k,n]  (f32 atomics)
//  2) sg_gemm:    ctx[k,c] += sum_n p[k,n] * feats[c,n]   (bf16 MFMA, C split in half across blocks)
//  3) sg_epi:     out = ctx / max(colsum,1e-6)
// Rationale: the fused kernel was latency-bound (occ 23%: acc=160 regs/lane + 100KB LDS).
// Splitting lets the GEMM halve its accumulator (acc 80/lane -> 4 waves/SIMD) and drop to
// 1 barrier/chunk; softmax runs once in a light high-occupancy kernel.

#define N_PIX (512 * 512)            // 262144
#define K_CLS 150
#define C_DIM 512
#define KPAD 160

typedef short short8 __attribute__((ext_vector_type(8)));
typedef float floatx4 __attribute__((ext_vector_type(4)));

__device__ __forceinline__ unsigned short f2bf(float x) {
  unsigned u = __builtin_bit_cast(unsigned, x);
  u += 0x7FFFu + ((u >> 16) & 1u);
  return (unsigned short)(u >> 16);
}

__device__ __forceinline__ void async_ld16(const void* g, void* l) {
  __builtin_amdgcn_global_load_lds(
      (const __attribute__((address_space(1))) void*)g,
      (__attribute__((address_space(3))) void*)l, 16, 0, 0);
}
__device__ __forceinline__ void async_ld4(const void* g, void* l) {
  __builtin_amdgcn_global_load_lds(
      (const __attribute__((address_space(1))) void*)g,
      (__attribute__((address_space(3))) void*)l, 4, 0, 0);
}

// ---------------------------------------------------------------------------
// Kernel 1: softmax over classes, p -> bf16 [KPAD][N] (rows >=150 untouched)
// 1024 blocks x 512 thr, 256 px/block, chunks of 32 px, LDS 41.6KB -> 3 blk/CU
// ---------------------------------------------------------------------------
#define K1_PIX 256
#define K1_NCH 8

__global__ __launch_bounds__(512, 6) void sg_softmax(
    const float* __restrict__ logits, unsigned short* __restrict__ pg,
    float* __restrict__ colsum_g)
{
  __shared__ float lraw[2][152][32];   // 150 rows + 2 pad for DMA tail
  __shared__ float part[16][32];
  __shared__ float csum[K_CLS];

  const int tid  = threadIdx.x;
  const int w    = tid >> 6;
  const int lane = tid & 63;
  const int hi   = lane >> 5;          // half-wave
  const int px   = lane & 31;          // pixel within chunk
  const int nbase = blockIdx.x * K1_PIX;

  if (tid < K_CLS) csum[tid] = 0.f;

  // DMA one 32-px logits chunk: instr t covers rows 8t..8t+7 (128B each),
  // lane l -> row 8t+(l>>3) (src clamped to 149; dest rows 150/151 are pad)
  auto stage = [&](int ci, int buf) {
#pragma unroll
    for (int u = 0; u < 3; ++u) {
      const int t = w + 8 * u;
      if (t < 19) {
        int row = 8 * t + (lane >> 3);
        if (row > 149) row = 149;
        async_ld16(logits + (size_t)row * N_PIX + nbase + ci * 32 + (lane & 7) * 4,
                   &lraw[buf][8 * t][0]);
      }
    }
  };
  stage(0, 0);

  for (int ci = 0; ci < K1_NCH; ++ci) {
    const int buf = ci & 1;
    __syncthreads();                   // chunk ci staged (drains DMA)

    // phase 1a: denominator partials; group g=2w+hi owns rows g+16i
    float sp = 0.f;
    const int g = 2 * w + hi;
#pragma unroll
    for (int i = 0; i < 10; ++i) {
      const int k = g + 16 * i;
      if (k < K_CLS) sp += __expf(lraw[buf][k][px]);
    }
    part[g][px] = sp;
    __syncthreads();
    float s = 0.f;
#pragma unroll
    for (int gg = 0; gg < 16; ++gg) s += part[gg][px];
    const float rs = 1.0f / s;

    // prefetch next chunk under phase 1b
    if (ci + 1 < K1_NCH) stage(ci + 1, buf ^ 1);

    // phase 1b: p -> bf16 global (coalesced 64B per half-wave) + colsum
#pragma unroll
    for (int i = 0; i < 10; ++i) {
      const int k = w + 16 * i + 8 * hi;
      if (k < K_CLS) {
        const float p = __expf(lraw[buf][k][px]) * rs;
        pg[(size_t)k * N_PIX + nbase + ci * 32 + px] = f2bf(p);
        float r = p;
        r += __shfl_xor(r, 16);
        r += __shfl_xor(r, 8);
        r += __shfl_xor(r, 4);
        r += __shfl_xor(r, 2);
        r += __shfl_xor(r, 1);
        if (px == 0) csum[k] += r;     // row k owned exclusively by (w,hi,i)
      }
    }
  }
  __syncthreads();
  if (tid < K_CLS) atomicAdd(&colsum_g[tid], csum[tid]);
}

// ---------------------------------------------------------------------------
// Kernel 2: pure GEMM ctx[k,c] += p[k,n]*feats[c,n].
// 512 blocks: (bid>>1)=px-part (1024 px), (bid&1)=C-half (256 cols).
// acc[2][10] = 80 regs/lane; atile dbuf 40KB; 1 barrier per 64-px chunk.
// A-fragments DMA-gathered from row-major p via per-lane source addresses.
// ---------------------------------------------------------------------------
#define K2_PIX 1024
#define K2_NCH 16

__global__ __launch_bounds__(512, 4) void sg_gemm(
    const float* __restrict__ feats, const unsigned short* __restrict__ pg,
    float* __restrict__ ctx)
{
  __shared__ unsigned short atile[2][20 * 64 * 8];   // [buf][slot t=rg*2+ks][lin][e]

  const int tid  = threadIdx.x;
  const int w    = tid >> 6;
  const int lane = tid & 63;
  const int quad = lane >> 4;
  const int l15  = lane & 15;
  const int pxbase = (blockIdx.x >> 1) * K2_PIX;
  const int cbase  = (blockIdx.x & 1) * 256;

  // DMA A-fragments: slot t (rg=t>>1, ks=t&1): lane l writes 16B at atile+t*1024+l*16
  // holding p[k=rg*16+(l&15)][n0+ks*32+(l>>4)*8 .. +7] -- exact MFMA A layout.
  auto stage = [&](int ci, int buf) {
#pragma unroll
    for (int u = 0; u < 3; ++u) {
      const int t = w + 8 * u;
      if (t < 20) {
        const int rg = t >> 1, ks = t & 1;
        async_ld16(pg + (size_t)(rg * 16 + l15) * N_PIX + pxbase + ci * 64 + ks * 32 + quad * 8,
                   &atile[buf][t * 512]);
      }
    }
  };

  floatx4 acc[2][10];
#pragma unroll
  for (int j = 0; j < 2; ++j)
#pragma unroll
    for (int rg = 0; rg < 10; ++rg)
      acc[j][rg] = (floatx4){0.f, 0.f, 0.f, 0.f};

  stage(0, 0);

  for (int ci = 0; ci < K2_NCH; ++ci) {
    const int buf = ci & 1;
    const int n0  = pxbase + ci * 64;
    __syncthreads();                   // atile[buf] staged; buf^1 free for prefetch

    // feats k-step 0 loads
    floatx4 breg[4];
#pragma unroll
    for (int j = 0; j < 2; ++j) {
      const float* bp = feats + (size_t)(cbase + (w + 8 * j) * 16 + l15) * N_PIX + n0 + quad * 8;
      breg[2 * j]     = *(const floatx4*)bp;
      breg[2 * j + 1] = *(const floatx4*)(bp + 4);
    }

    // prefetch next chunk's A-fragments (in flight across the MFMA phase)
    if (ci + 1 < K2_NCH) stage(ci + 1, buf ^ 1);

    // convert k-step 0
    short8 bfrag[2];
#pragma unroll
    for (int j = 0; j < 2; ++j) {
      floatx4 lo = breg[2 * j], hi = breg[2 * j + 1];
      short8 f;
      f[0] = f2bf(lo[0]); f[1] = f2bf(lo[1]); f[2] = f2bf(lo[2]); f[3] = f2bf(lo[3]);
      f[4] = f2bf(hi[0]); f[5] = f2bf(hi[1]); f[6] = f2bf(hi[2]); f[7] = f2bf(hi[3]);
      bfrag[j] = f;
    }

    // feats k-step 1 loads
    floatx4 breg2[4];
#pragma unroll
    for (int j = 0; j < 2; ++j) {
      const float* bp = feats + (size_t)(cbase + (w + 8 * j) * 16 + l15) * N_PIX + n0 + 32 + quad * 8;
      breg2[2 * j]     = *(const floatx4*)bp;
      breg2[2 * j + 1] = *(const floatx4*)(bp + 4);
    }

    // MFMA k-step 0
#pragma unroll
    for (int rg = 0; rg < 10; ++rg) {
      short8 afrag = *(const short8*)&atile[buf][(rg * 2 + 0) * 512 + lane * 8];
#pragma unroll
      for (int j = 0; j < 2; ++j)
        acc[j][rg] = __builtin_amdgcn_mfma_f32_16x16x32_bf16(afrag, bfrag[j], acc[j][rg], 0, 0, 0);
    }

    // convert k-step 1
#pragma unroll
    for (int j = 0; j < 2; ++j) {
      floatx4 lo = breg2[2 * j], hi = breg2[2 * j + 1];
      short8 f;
      f[0] = f2bf(lo[0]); f[1] = f2bf(lo[1]); f[2] = f2bf(lo[2]); f[3] = f2bf(lo[3]);
      f[4] = f2bf(hi[0]); f[5] = f2bf(hi[1]); f[6] = f2bf(hi[2]); f[7] = f2bf(hi[3]);
      bfrag[j] = f;
    }

    // MFMA k-step 1
#pragma unroll
    for (int rg = 0; rg < 10; ++rg) {
      short8 afrag = *(const short8*)&atile[buf][(rg * 2 + 1) * 512 + lane * 8];
#pragma unroll
      for (int j = 0; j < 2; ++j)
        acc[j][rg] = __builtin_amdgcn_mfma_f32_16x16x32_bf16(afrag, bfrag[j], acc[j][rg], 0, 0, 0);
    }
  }

  // flush (C/D layout: col = lane&15, row = quad*4 + r)
#pragma unroll
  for (int j = 0; j < 2; ++j) {
    const int c = cbase + ((w + 8 * j) << 4) + l15;
#pragma unroll
    for (int rg = 0; rg < 10; ++rg) {
#pragma unroll
      for (int r = 0; r < 4; ++r) {
        const int row = rg * 16 + quad * 4 + r;
        if (row < K_CLS) atomicAdd(&ctx[row * C_DIM + c], acc[j][rg][r]);
      }
    }
  }
}

__global__ void sg_epi(const float* __restrict__ ctx, const float* __restrict__ colsum,
                       float* __restrict__ out)
{
  const int idx = blockIdx.x * 256 + threadIdx.x;
  if (idx < K_CLS * C_DIM) {
    const float d = fmaxf(colsum[idx >> 9], 1e-6f);
    out[idx] = ctx[idx] / d;
  }
}

// ---------------------------------------------------------------------------
// Fallback: previous fused single-kernel path (used if ws_size < ~84MB)
// ---------------------------------------------------------------------------
#define NBLK 256
#define PIX_PER_BLK (N_PIX / NBLK)   // 1024
#define CHUNK 64
#define NCHUNK (PIX_PER_BLK / CHUNK) // 16

__global__ __launch_bounds__(512) void sg_main(
    const float* __restrict__ feats, const float* __restrict__ logits,
    float* __restrict__ ctx, float* __restrict__ colsum_g)
{
  __shared__ float lraw[2][K_CLS][CHUNK];
  __shared__ unsigned short atile[20 * 64 * 8];
  __shared__ float part[8][64];
  __shared__ float colsum_lds[K_CLS];

  const int tid  = threadIdx.x;
  const int w    = tid >> 6;
  const int lane = tid & 63;
  const int quad = lane >> 4;
  const int l15  = lane & 15;
  const int nbase = blockIdx.x * PIX_PER_BLK;

  for (int i = tid; i < 20 * 64 * 8 / 2; i += 512) ((unsigned*)atile)[i] = 0u;
  if (tid < K_CLS) colsum_lds[tid] = 0.f;

  floatx4 acc[4][10];
#pragma unroll
  for (int j = 0; j < 4; ++j)
#pragma unroll
    for (int rg = 0; rg < 10; ++rg)
      acc[j][rg] = (floatx4){0.f, 0.f, 0.f, 0.f};

#pragma unroll
  for (int i = 0; i < 19; ++i) {
    const int k = w + 8 * i;
    if (k < K_CLS)
      async_ld4(logits + (size_t)k * N_PIX + nbase + lane, &lraw[0][k][0]);
  }

  for (int ci = 0; ci < NCHUNK; ++ci) {
    __syncthreads();
    const int buf = ci & 1;
    const int n0  = nbase + ci * CHUNK;

    floatx4 breg[8];
#pragma unroll
    for (int j = 0; j < 4; ++j) {
      const float* bp = feats + (size_t)((w + 8 * j) * 16 + l15) * N_PIX + n0 + quad * 8;
      breg[2 * j]     = *(const floatx4*)bp;
      breg[2 * j + 1] = *(const floatx4*)(bp + 4);
    }

    float s_part = 0.f;
#pragma unroll
    for (int i = 0; i < 19; ++i) {
      const int k = w + 8 * i;
      if (k < K_CLS) s_part += __expf(lraw[buf][k][lane]);
    }
    part[w][lane] = s_part;
    __syncthreads();
    float s = 0.f;
#pragma unroll
    for (int ww = 0; ww < 8; ++ww) s += part[ww][lane];
    const float rs = 1.0f / s;

#pragma unroll
    for (int i = 0; i < 19; ++i) {
      const int k = w + 8 * i;
      if (k < K_CLS) {
        const float p = __expf(lraw[buf][k][lane]) * rs;
        const int fid = ((k >> 4) << 1) + (lane >> 5);
        const int lin = (k & 15) | (((lane >> 3) & 3) << 4);
        atile[(fid * 64 + lin) * 8 + (lane & 7)] = f2bf(p);
        float r = p;
        r += __shfl_xor(r, 32);
        r += __shfl_xor(r, 16);
        r += __shfl_xor(r, 8);
        r += __shfl_xor(r, 4);
        r += __shfl_xor(r, 2);
        r += __shfl_xor(r, 1);
        if (lane == 0) colsum_lds[k] += r;
      }
    }
    __syncthreads();

    short8 bfrag[4];
#pragma unroll
    for (int j = 0; j < 4; ++j) {
      floatx4 lo = breg[2 * j], hi = breg[2 * j + 1];
      short8 f;
      f[0] = f2bf(lo[0]); f[1] = f2bf(lo[1]); f[2] = f2bf(lo[2]); f[3] = f2bf(lo[3]);
      f[4] = f2bf(hi[0]); f[5] = f2bf(hi[1]); f[6] = f2bf(hi[2]); f[7] = f2bf(hi[3]);
      bfrag[j] = f;
    }

#pragma unroll
    for (int j = 0; j < 4; ++j) {
      const float* bp = feats + (size_t)((w + 8 * j) * 16 + l15) * N_PIX + n0 + 32 + quad * 8;
      breg[2 * j]     = *(const floatx4*)bp;
      breg[2 * j + 1] = *(const floatx4*)(bp + 4);
    }

    if (ci + 1 < NCHUNK) {
#pragma unroll
      for (int i = 0; i < 19; ++i) {
        const int k = w + 8 * i;
        if (k < K_CLS)
          async_ld4(logits + (size_t)k * N_PIX + n0 + CHUNK + lane, &lraw[buf ^ 1][k][0]);
      }
    }

#pragma unroll
    for (int rg = 0; rg < 10; ++rg) {
      short8 afrag = *(const short8*)&atile[((rg * 2 + 0) * 64 + lane) * 8];
#pragma unroll
      for (int j = 0; j < 4; ++j)
        acc[j][rg] = __builtin_amdgcn_mfma_f32_16x16x32_bf16(afrag, bfrag[j], acc[j][rg], 0, 0, 0);
    }

#pragma unroll
    for (int j = 0; j < 4; ++j) {
      floatx4 lo = breg[2 * j], hi = breg[2 * j + 1];
      short8 f;
      f[0] = f2bf(lo[0]); f[1] = f2bf(lo[1]); f[2] = f2bf(lo[2]); f[3] = f2bf(lo[3]);
      f[4] = f2bf(hi[0]); f[5] = f2bf(hi[1]); f[6] = f2bf(hi[2]); f[7] = f2bf(hi[3]);
      bfrag[j] = f;
    }

#pragma unroll
    for (int rg = 0; rg < 10; ++rg) {
      short8 afrag = *(const short8*)&atile[((rg * 2 + 1) * 64 + lane) * 8];
#pragma unroll
      for (int j = 0; j < 4; ++j)
        acc[j][rg] = __builtin_amdgcn_mfma_f32_16x16x32_bf16(afrag, bfrag[j], acc[j][rg], 0, 0, 0);
    }
  }

#pragma unroll
  for (int j = 0; j < 4; ++j) {
    const int c = ((w + 8 * j) << 4) + l15;
#pragma unroll
    for (int rg = 0; rg < 10; ++rg) {
#pragma unroll
      for (int r = 0; r < 4; ++r) {
        const int row = rg * 16 + quad * 4 + r;
        if (row < K_CLS) atomicAdd(&ctx[row * C_DIM + c], acc[j][rg][r]);
      }
    }
  }
  __syncthreads();
  if (tid < K_CLS) atomicAdd(&colsum_g[tid], colsum_lds[tid]);
}

extern "C" void kernel_launch(void* const* d_in, const int* in_sizes, int n_in,
                              void* d_out, int out_size, void* d_ws, size_t ws_size,
                              hipStream_t stream)
{
  const float* feats  = (const float*)d_in[0];   // (512, 262144) fp32
  const float* logits = (const float*)d_in[1];   // (150, 262144) fp32

  const size_t pg_bytes = (size_t)KPAD * N_PIX * sizeof(unsigned short);  // 83.9 MB
  const size_t acc_bytes = (size_t)(K_CLS * C_DIM + K_CLS) * sizeof(float);

  if (ws_size >= pg_bytes + acc_bytes) {
    unsigned short* pg = (unsigned short*)d_ws;
    float* ctx    = (float*)((char*)d_ws + pg_bytes);
    float* colsum = ctx + K_CLS * C_DIM;
    hipMemsetAsync(ctx, 0, acc_bytes, stream);
    sg_softmax<<<dim3(1024), dim3(512), 0, stream>>>(logits, pg, colsum);
    sg_gemm<<<dim3(512), dim3(512), 0, stream>>>(feats, pg, ctx);
    sg_epi<<<dim3((K_CLS * C_DIM + 255) / 256), dim3(256), 0, stream>>>(ctx, colsum, (float*)d_out);
  } else {
    float* ctx    = (float*)d_ws;
    float* colsum = ctx + K_CLS * C_DIM;
    hipMemsetAsync(d_ws, 0, acc_bytes, stream);
    sg_main<<<dim3(NBLK), dim3(512), 0, stream>>>(feats, logits, ctx, colsum);
    sg_epi<<<dim3((K_CLS * C_DIM + 255) / 256), dim3(256), 0, stream>>>(ctx, colsum, (float*)d_out);
  }
}